// Round 8
// baseline (154.948 us; speedup 1.0000x reference)
//
#include <hip/hip_runtime.h>
#include <stdint.h>

#define NBOX 8000
#define NPAD 8192
#define NW   128      // 64-bit words per mask row (stride)
#define LCAP 16       // per-row sparse list capacity (u16 entries)
#define LFAST 8       // list entries kept in registers by scan
#define VLIM 4224     // list path valid while V <= VLIM (V~4000 here)

// ---- workspace layout (bytes) ----
#define COUNT_OFF 0
#define VKEYS_OFF 0x9000                     // 8192 * 8
#define U_OFF     0x20000                    // 6 unsorted arrays
#define UARR(i)   (U_OFF + (size_t)(i) * NPAD * 4)   // bx,by,bw,bh,conf,cls
#define SIDX_OFF  0x50000                    // int[8192]
#define SARR(i)   (0x58000 + (size_t)(i) * NPAD * 4) // x1,y1,x2,y2,area,cls
#define KEEP_OFF  0x98000                    // 128 * 8
#define CNT_OFF   0x99000                    // 4352 * 4 (zeroed by rank_scatter)
#define MASK_OFF  (size_t)0xA0000            // rows < V; V<=VLIM keeps it under LIST_OFF
#define LIST_OFF  (size_t)0x4C0000           // 4224 * 16 * 2B (used when V<=VLIM)

__device__ __forceinline__ float sigmoidf_(float x) {
    return 1.0f / (1.0f + expf(-x));
}

__device__ __forceinline__ unsigned long long readlane64(unsigned long long v, int l) {
    unsigned int lo = (unsigned int)__builtin_amdgcn_readlane((int)(unsigned int)(v & 0xffffffffull), l);
    unsigned int hi = (unsigned int)__builtin_amdgcn_readlane((int)(unsigned int)(v >> 32), l);
    return ((unsigned long long)hi << 32) | (unsigned long long)lo;
}

// entry t (0..7) from a u64 pair (t0..3 in lo, t4..7 in hi)
__device__ __forceinline__ unsigned int ent16(unsigned long long lo, unsigned long long hi, int t) {
    unsigned long long src = (t < 4) ? lo : hi;
    return (unsigned int)((src >> ((t & 3) << 4)) & 0xFFFFull);
}

// ---------------- decode: 1 wave/block, wave-aggregated key compaction ----------------
__global__ __launch_bounds__(64) void decode_kernel(const float* __restrict__ x,
                                                    const float* __restrict__ anchors,
                                                    unsigned char* __restrict__ ws) {
    int n = blockIdx.x * 64 + threadIdx.x;          // 125*64 = 8000 exactly
    int a   = n / 1600;
    int pos = n - a * 1600;
    int gy  = pos / 40;
    int gx  = pos - gy * 40;
    const float* p = x + (size_t)a * 25 * 1600 + pos;

    float tx   = sigmoidf_(p[0]);
    float ty   = sigmoidf_(p[1600]);
    float tw   = p[2 * 1600];
    float th   = p[3 * 1600];
    float conf = sigmoidf_(p[4 * 1600]);

    float best = -1.0f; int bi = 0;
    #pragma unroll
    for (int c = 0; c < 20; ++c) {                  // first-max wins, matches jnp.argmax
        float v = sigmoidf_(p[(5 + c) * 1600]);
        if (v > best) { best = v; bi = c; }
    }

    float aw = anchors[a * 2 + 0];
    float ah = anchors[a * 2 + 1];
    float bx = (tx + (float)gx) * 8.0f;
    float by = (ty + (float)gy) * 8.0f;
    float bw = expf(tw) * aw * 8.0f;
    float bh = expf(th) * ah * 8.0f;

    ((float*)(ws + UARR(0)))[n] = bx;
    ((float*)(ws + UARR(1)))[n] = by;
    ((float*)(ws + UARR(2)))[n] = bw;
    ((float*)(ws + UARR(3)))[n] = bh;
    ((float*)(ws + UARR(4)))[n] = conf;
    ((float*)(ws + UARR(5)))[n] = (float)bi;

    bool valid = conf > 0.5f;                       // strict >, matches ref
    unsigned long long bal = __ballot(valid);
    if (bal) {
        int lead = __builtin_ctzll(bal);
        unsigned int base = 0;
        if ((int)threadIdx.x == lead)
            base = atomicAdd((unsigned int*)(ws + COUNT_OFF), (unsigned int)__popcll(bal));
        base = (unsigned int)__shfl((int)base, lead, 64);
        if (valid) {
            unsigned int cb = __float_as_uint(conf);   // conf in (0,1): bits monotonic
            unsigned long long key = ((unsigned long long)cb << 32) | (unsigned long long)(8191 - n);
            unsigned int slot = base + (unsigned int)__popcll(bal & ((1ull << threadIdx.x) - 1ull));
            ((unsigned long long*)(ws + VKEYS_OFF))[slot] = key;
        }
    }
}

// ---------------- block-complete rank + scatter (one pass, no atomics) ----------------
__global__ __launch_bounds__(256) void rank_scatter_kernel(unsigned char* __restrict__ ws) {
#pragma clang fp contract(off)
    __shared__ unsigned long long tile[256];
    __shared__ int partial[256];
    int V = *(const int*)(ws + COUNT_OFF);
    if (V > NPAD) V = NPAD;
    int tid  = threadIdx.x;
    int lane = tid & 63;
    int q    = tid >> 6;                            // quarter 0..3
    int b    = blockIdx.x;                          // 128 blocks
    int i    = (b << 6) + lane;                     // row owned by this lane
    int gtid = b * 256 + tid;
    if (gtid < 4352) ((unsigned int*)(ws + CNT_OFF))[gtid] = 0u;   // zero list counts

    const unsigned long long* vk = (const unsigned long long*)(ws + VKEYS_OFF);
    unsigned long long ki = (i < V) ? vk[i] : ~0ull;
    int cnt = 0;
    if ((b << 6) < V) {                             // block-uniform
        int ntiles = (V + 255) >> 8;
        for (int tb = 0; tb < ntiles; ++tb) {
            int j = (tb << 8) + tid;
            tile[tid] = (j < V) ? vk[j] : 0ull;     // pad 0 never counts (keys > 0)
            __syncthreads();
            int basej = (tb << 8) + (q << 6);
            int lim = V - basej;
            if (lim > 64) lim = 64;
            const unsigned long long* tq = &tile[q << 6];
            if (lim == 64) {
                #pragma unroll 16
                for (int jj = 0; jj < 64; ++jj) cnt += (tq[jj] > ki) ? 1 : 0;
            } else {
                for (int jj = 0; jj < lim; ++jj) cnt += (tq[jj] > ki) ? 1 : 0;
            }
            __syncthreads();
        }
    }
    partial[tid] = cnt;
    __syncthreads();
    if (q == 0) {
        float* sx1 = (float*)(ws + SARR(0));
        float* sy1 = (float*)(ws + SARR(1));
        float* sx2 = (float*)(ws + SARR(2));
        float* sy2 = (float*)(ws + SARR(3));
        float* sar = (float*)(ws + SARR(4));
        float* scl = (float*)(ws + SARR(5));
        if (i < V) {
            int r = partial[lane] + partial[64 + lane] + partial[128 + lane] + partial[192 + lane];
            int idx = 8191 - (int)(ki & 0x1FFFull);
            ((int*)(ws + SIDX_OFF))[r] = idx;
            float cx = ((float*)(ws + UARR(0)))[idx];
            float cy = ((float*)(ws + UARR(1)))[idx];
            float w  = ((float*)(ws + UARR(2)))[idx];
            float h  = ((float*)(ws + UARR(3)))[idx];
            float x1 = cx - w / 2.0f;
            float y1 = cy - h / 2.0f;
            float x2 = cx + w / 2.0f;
            float y2 = cy + h / 2.0f;
            sx1[r] = x1; sy1[r] = y1; sx2[r] = x2; sy2[r] = y2;
            sar[r] = fabsf((x2 - x1) * (y2 - y1));  // ref: recomputed from corners
            scl[r] = ((float*)(ws + UARR(5)))[idx];
        } else {                                    // rank positions [V, NPAD): defaults
            ((int*)(ws + SIDX_OFF))[i] = -1;
            sx1[i] = 0.f; sy1[i] = 0.f; sx2[i] = 0.f; sy2[i] = 0.f;
            sar[i] = 0.f; scl[i] = -1.0f;
        }
    }
}

// ---------------- suppression bitmask + sparse per-row column lists ----------------
__global__ __launch_bounds__(256) void mask_kernel(unsigned char* __restrict__ ws) {
#pragma clang fp contract(off)
    int V = *(int*)(ws + COUNT_OFF);
    if (V > NPAD) V = NPAD;
    int i0 = blockIdx.y * 256;
    int w  = blockIdx.x;
    int j0 = w * 64;
    if (i0 >= V) return;
    if (j0 >= V) return;
    if (j0 + 64 <= i0) return;                     // strictly sub-diagonal: all zero
    int i  = i0 + threadIdx.x;

    const float* sx1 = (const float*)(ws + SARR(0));
    const float* sy1 = (const float*)(ws + SARR(1));
    const float* sx2 = (const float*)(ws + SARR(2));
    const float* sy2 = (const float*)(ws + SARR(3));
    const float* sar = (const float*)(ws + SARR(4));
    const float* scl = (const float*)(ws + SARR(5));

    __shared__ float cx1[64], cy1[64], cx2[64], cy2[64], car[64], ccl[64];
    if (threadIdx.x < 64) {
        int j = j0 + threadIdx.x;
        cx1[threadIdx.x] = sx1[j]; cy1[threadIdx.x] = sy1[j];
        cx2[threadIdx.x] = sx2[j]; cy2[threadIdx.x] = sy2[j];
        car[threadIdx.x] = sar[j]; ccl[threadIdx.x] = scl[j];
    }
    __syncthreads();
    if (i >= V) return;

    unsigned long long word = 0;
    if (j0 + 64 > i + 1) {
        float x1i = sx1[i], y1i = sy1[i], x2i = sx2[i], y2i = sy2[i];
        float ai = sar[i], ci = scl[i];
        for (int jj = 0; jj < 64; ++jj) {
            int j = j0 + jj;
            if (j <= i || j >= V) continue;
            if (ccl[jj] != ci) continue;
            float iw = fminf(x2i, cx2[jj]) - fmaxf(x1i, cx1[jj]);
            iw = fmaxf(iw, 0.0f);
            float ih = fminf(y2i, cy2[jj]) - fmaxf(y1i, cy1[jj]);
            ih = fmaxf(ih, 0.0f);
            float inter = iw * ih;
            float denom = ai + car[jj] - inter + 1e-6f;   // ((ai+aj)-inter)+eps, L-to-R
            if (inter / denom >= 0.5f) word |= (1ull << jj);
        }
    }
    ((unsigned long long*)(ws + MASK_OFF))[(size_t)i * NW + w] = word;

    if (word && V <= VLIM) {                       // sparse list emission
        int pc = __popcll(word);
        unsigned int b = atomicAdd((unsigned int*)(ws + CNT_OFF) + i, (unsigned int)pc);
        unsigned long long t = word;
        unsigned int o = 0;
        while (t) {
            int bit = __builtin_ctzll(t);
            t &= t - 1ull;
            unsigned int slot = b + o; ++o;
            if (slot < LCAP)
                ((unsigned short*)(ws + LIST_OFF))[(size_t)i * LCAP + slot] =
                    (unsigned short)(j0 + bit);
        }
    }
}

// ---------------- greedy scan: ONE wave, group-of-8 deep register prefetch ----------------
// supp = u64[128] in LDS. Per 64-row chunk the serial path is only:
//   ds_read supp[c] -> scalar greedy resolve (ctz loop over suppressor rows)
//   -> register-list scatter (LDS atomicOr). All memory (cnt, first-8 list
// entries, diag mask word) is prefetched 8-16 chunks ahead in registers, so
// cross-XCD L2 latency is fully hidden. Rows with 8<cnt<=16 load the list's
// second half on demand (rare); cnt>16 falls back to reading mask-row words.

#define LOADG(CN, LA, LB, IW, G) do {                                          \
    int g_ = (G);                                                              \
    _Pragma("unroll") for (int d_ = 0; d_ < 8; ++d_) {                         \
        int cc_  = g_ * 8 + d_;                                                \
        int row_ = (cc_ << 6) + lane;                                          \
        CN[d_] = 0x7FFFFFFFu; LA[d_] = 0; LB[d_] = 0; IW[d_] = 0;              \
        if (cc_ < nch && row_ < V) {                                           \
            if (useL) {                                                        \
                CN[d_] = cnt[row_];                                            \
                ulonglong2 t2_ = lst[(size_t)row_ * 2];                        \
                LA[d_] = t2_.x; LB[d_] = t2_.y;                                \
            }                                                                  \
            IW[d_] = mask[(size_t)row_ * NW + cc_];                            \
        }                                                                      \
    }                                                                          \
} while (0)

__global__ __launch_bounds__(64, 1) void scan_kernel(unsigned char* __restrict__ ws) {
    int lane = threadIdx.x;
    int V = *(const int*)(ws + COUNT_OFF);
    if (V > NPAD) V = NPAD;
    const unsigned long long* mask = (const unsigned long long*)(ws + MASK_OFF);
    const unsigned int*  cnt = (const unsigned int*)(ws + CNT_OFF);
    const ulonglong2*    lst = (const ulonglong2*)(ws + LIST_OFF);
    unsigned long long*  keepw = (unsigned long long*)(ws + KEEP_OFF);

    __shared__ unsigned long long supp[128];       // 8192-bit suppression bitmap
    supp[lane] = 0ull; supp[64 + lane] = 0ull;     // same-wave DS ordering, no barrier

    int nch  = (V + 63) >> 6;
    int maxw = nch;
    bool useL = (V <= VLIM);

    unsigned int cnA[8], cnB[8];
    unsigned long long laA[8], lbA[8], iwA[8], laB[8], lbB[8], iwB[8];

    int ngr = (nch + 7) >> 3;
    if (ngr > 0) LOADG(cnA, laA, lbA, iwA, 0);

    for (int g = 0; g < ngr; ++g) {
        if (g + 1 < ngr) LOADG(cnB, laB, lbB, iwB, g + 1);   // ~24 loads in flight

        #pragma unroll
        for (int d = 0; d < 8; ++d) {
            int c = g * 8 + d;
            if (c < nch) {
                int base = c << 6;
                int row  = base + lane;

                unsigned long long aw = supp[c];             // LDS broadcast read
                int rem = V - base;
                unsigned long long tail = (rem >= 64) ? ~0ull : ((1ull << rem) - 1ull);
                unsigned long long alive = ~aw & tail;

                unsigned long long inw = iwA[d];             // diag mask word (prefetched)
                unsigned long long dnz = __ballot(inw != 0ull);
                unsigned long long work = alive & dnz;
                while (work) {                               // greedy resolve (scalar unit)
                    int k = __builtin_ctzll(work);
                    work &= work - 1ull;
                    unsigned long long dk = readlane64(inw, k);
                    alive &= ~dk;
                    work  &= ~dk;
                }

                bool am = ((alive >> lane) & 1ull) && (row < V);
                unsigned int cA = cnA[d];
                if (am && cA <= LFAST) {                     // common: register list
                    for (unsigned int t = 0; t < cA; ++t) {
                        unsigned int j = ent16(laA[d], lbA[d], (int)t);
                        atomicOr(&supp[j >> 6], 1ull << (j & 63));
                    }
                } else if (am && cA <= LCAP) {               // rare: load 2nd half now
                    ulonglong2 hi = lst[(size_t)row * 2 + 1];
                    for (unsigned int t = 0; t < cA; ++t) {
                        unsigned int j = (t < LFAST) ? ent16(laA[d], lbA[d], (int)t)
                                                     : ent16(hi.x, hi.y, (int)(t - LFAST));
                        atomicOr(&supp[j >> 6], 1ull << (j & 63));
                    }
                }
                unsigned long long ofl = __ballot(am && cA > LCAP);   // overflow / fallback
                while (ofl) {
                    int k = __builtin_ctzll(ofl);
                    ofl &= ofl - 1ull;
                    size_t rb = (size_t)(base + k) * NW;
                    for (int ww = c + lane; ww < maxw; ww += 64) {
                        unsigned long long m = mask[rb + ww];
                        if (m) atomicOr(&supp[ww], m);
                    }
                }
            }
        }

        #pragma unroll
        for (int d = 0; d < 8; ++d) {                        // B -> A
            cnA[d] = cnB[d]; laA[d] = laB[d]; lbA[d] = lbB[d]; iwA[d] = iwB[d];
        }
    }

    keepw[lane]      = ~supp[lane];
    keepw[64 + lane] = ~supp[64 + lane];
}

// ---------------- write output ----------------
__global__ __launch_bounds__(256) void output_kernel(const unsigned char* __restrict__ ws,
                                                     float* __restrict__ out) {
    int r = blockIdx.x * 256 + threadIdx.x;
    if (r >= NBOX) return;
    int V = *(const int*)(ws + COUNT_OFF);
    if (V > NPAD) V = NPAD;
    const unsigned long long* keepw = (const unsigned long long*)(ws + KEEP_OFF);
    bool keep = (r < V) && ((keepw[r >> 6] >> (r & 63)) & 1ull);
    float o0 = 0.f, o1 = 0.f, o2 = 0.f, o3 = 0.f, o4 = 0.f, o5 = 0.f;
    if (keep) {
        int idx = ((const int*)(ws + SIDX_OFF))[r];
        if (idx >= 0 && idx < NBOX) {
            o0 = ((const float*)(ws + UARR(0)))[idx];
            o1 = ((const float*)(ws + UARR(1)))[idx];
            o2 = ((const float*)(ws + UARR(2)))[idx];
            o3 = ((const float*)(ws + UARR(3)))[idx];
            o4 = ((const float*)(ws + UARR(4)))[idx];
            o5 = ((const float*)(ws + UARR(5)))[idx];
        }
    }
    out[r * 6 + 0] = o0;
    out[r * 6 + 1] = o1;
    out[r * 6 + 2] = o2;
    out[r * 6 + 3] = o3;
    out[r * 6 + 4] = o4;
    out[r * 6 + 5] = o5;
}

extern "C" void kernel_launch(void* const* d_in, const int* in_sizes, int n_in,
                              void* d_out, int out_size, void* d_ws, size_t ws_size,
                              hipStream_t stream) {
    const float* x       = (const float*)d_in[0];
    const float* anchors = (const float*)d_in[1];
    float* out           = (float*)d_out;
    unsigned char* ws    = (unsigned char*)d_ws;

    hipMemsetAsync(ws + COUNT_OFF, 0, 4, stream);          // zero valid-count only
    decode_kernel<<<125, 64, 0, stream>>>(x, anchors, ws);
    rank_scatter_kernel<<<NPAD / 64, 256, 0, stream>>>(ws);
    dim3 mgrid(NW, NPAD / 256);
    mask_kernel<<<mgrid, 256, 0, stream>>>(ws);
    scan_kernel<<<1, 64, 0, stream>>>(ws);
    output_kernel<<<(NBOX + 255) / 256, 256, 0, stream>>>(ws, out);
}

// Round 9
// 151.383 us; speedup vs baseline: 1.0235x; 1.0235x over previous
//
#include <hip/hip_runtime.h>
#include <stdint.h>

#define NBOX 8000
#define NPAD 8192
#define NW   128      // 64-bit words per mask row (stride)
#define LCAP 16       // per-row sparse list capacity (u16 entries)
#define LFAST 8       // list entries kept in registers by scan
#define VLIM 4224     // list path valid while V <= VLIM (V~4000 here)

// ---- workspace layout (bytes) ----
#define COUNT_OFF 0
#define VKEYS_OFF 0x9000                     // 8192 * 8
#define U_OFF     0x20000                    // 6 unsorted arrays
#define UARR(i)   (U_OFF + (size_t)(i) * NPAD * 4)   // bx,by,bw,bh,conf,cls
#define SIDX_OFF  0x50000                    // int[8192]
#define SARR(i)   (0x58000 + (size_t)(i) * NPAD * 4) // x1,y1,x2,y2,area,cls
#define KEEP_OFF  0x98000                    // 128 * 8
#define CNT_OFF   0x99000                    // 4352 * 4 (zeroed by rank_scatter)
#define DIAG_OFF  0x9E000                    // 8192 * 8 compact diag words (coalesced)
#define MASK_OFF  (size_t)0xB0000            // rows < V; V<=VLIM keeps it under LIST_OFF
#define LIST_OFF  (size_t)0x4D0000           // 4224 * 32 B (used when V<=VLIM)

__device__ __forceinline__ float sigmoidf_(float x) {
    return 1.0f / (1.0f + expf(-x));
}

__device__ __forceinline__ unsigned long long readlane64(unsigned long long v, int l) {
    unsigned int lo = (unsigned int)__builtin_amdgcn_readlane((int)(unsigned int)(v & 0xffffffffull), l);
    unsigned int hi = (unsigned int)__builtin_amdgcn_readlane((int)(unsigned int)(v >> 32), l);
    return ((unsigned long long)hi << 32) | (unsigned long long)lo;
}

// entry t (0..7) from a u64 pair (t0..3 in lo, t4..7 in hi)
__device__ __forceinline__ unsigned int ent16(unsigned long long lo, unsigned long long hi, int t) {
    unsigned long long src = (t < 4) ? lo : hi;
    return (unsigned int)((src >> ((t & 3) << 4)) & 0xFFFFull);
}

// ---------------- decode: 1 wave/block, wave-aggregated key compaction ----------------
__global__ __launch_bounds__(64) void decode_kernel(const float* __restrict__ x,
                                                    const float* __restrict__ anchors,
                                                    unsigned char* __restrict__ ws) {
    int n = blockIdx.x * 64 + threadIdx.x;          // 125*64 = 8000 exactly
    int a   = n / 1600;
    int pos = n - a * 1600;
    int gy  = pos / 40;
    int gx  = pos - gy * 40;
    const float* p = x + (size_t)a * 25 * 1600 + pos;

    float tx   = sigmoidf_(p[0]);
    float ty   = sigmoidf_(p[1600]);
    float tw   = p[2 * 1600];
    float th   = p[3 * 1600];
    float conf = sigmoidf_(p[4 * 1600]);

    float best = -1.0f; int bi = 0;
    #pragma unroll
    for (int c = 0; c < 20; ++c) {                  // first-max wins, matches jnp.argmax
        float v = sigmoidf_(p[(5 + c) * 1600]);
        if (v > best) { best = v; bi = c; }
    }

    float aw = anchors[a * 2 + 0];
    float ah = anchors[a * 2 + 1];
    float bx = (tx + (float)gx) * 8.0f;
    float by = (ty + (float)gy) * 8.0f;
    float bw = expf(tw) * aw * 8.0f;
    float bh = expf(th) * ah * 8.0f;

    ((float*)(ws + UARR(0)))[n] = bx;
    ((float*)(ws + UARR(1)))[n] = by;
    ((float*)(ws + UARR(2)))[n] = bw;
    ((float*)(ws + UARR(3)))[n] = bh;
    ((float*)(ws + UARR(4)))[n] = conf;
    ((float*)(ws + UARR(5)))[n] = (float)bi;

    bool valid = conf > 0.5f;                       // strict >, matches ref
    unsigned long long bal = __ballot(valid);
    if (bal) {
        int lead = __builtin_ctzll(bal);
        unsigned int base = 0;
        if ((int)threadIdx.x == lead)
            base = atomicAdd((unsigned int*)(ws + COUNT_OFF), (unsigned int)__popcll(bal));
        base = (unsigned int)__shfl((int)base, lead, 64);
        if (valid) {
            unsigned int cb = __float_as_uint(conf);   // conf in (0,1): bits monotonic
            unsigned long long key = ((unsigned long long)cb << 32) | (unsigned long long)(8191 - n);
            unsigned int slot = base + (unsigned int)__popcll(bal & ((1ull << threadIdx.x) - 1ull));
            ((unsigned long long*)(ws + VKEYS_OFF))[slot] = key;
        }
    }
}

// ---------------- block-complete rank + scatter (one pass, no atomics) ----------------
__global__ __launch_bounds__(256) void rank_scatter_kernel(unsigned char* __restrict__ ws) {
#pragma clang fp contract(off)
    __shared__ unsigned long long tile[256];
    __shared__ int partial[256];
    int V = *(const int*)(ws + COUNT_OFF);
    if (V > NPAD) V = NPAD;
    int tid  = threadIdx.x;
    int lane = tid & 63;
    int q    = tid >> 6;                            // quarter 0..3
    int b    = blockIdx.x;                          // 128 blocks
    int i    = (b << 6) + lane;                     // row owned by this lane
    int gtid = b * 256 + tid;
    if (gtid < 4352) ((unsigned int*)(ws + CNT_OFF))[gtid] = 0u;   // zero list counts

    const unsigned long long* vk = (const unsigned long long*)(ws + VKEYS_OFF);
    unsigned long long ki = (i < V) ? vk[i] : ~0ull;
    int cnt = 0;
    if ((b << 6) < V) {                             // block-uniform
        int ntiles = (V + 255) >> 8;
        for (int tb = 0; tb < ntiles; ++tb) {
            int j = (tb << 8) + tid;
            tile[tid] = (j < V) ? vk[j] : 0ull;     // pad 0 never counts (keys > 0)
            __syncthreads();
            int basej = (tb << 8) + (q << 6);
            int lim = V - basej;
            if (lim > 64) lim = 64;
            const unsigned long long* tq = &tile[q << 6];
            if (lim == 64) {
                #pragma unroll 16
                for (int jj = 0; jj < 64; ++jj) cnt += (tq[jj] > ki) ? 1 : 0;
            } else {
                for (int jj = 0; jj < lim; ++jj) cnt += (tq[jj] > ki) ? 1 : 0;
            }
            __syncthreads();
        }
    }
    partial[tid] = cnt;
    __syncthreads();
    if (q == 0) {
        float* sx1 = (float*)(ws + SARR(0));
        float* sy1 = (float*)(ws + SARR(1));
        float* sx2 = (float*)(ws + SARR(2));
        float* sy2 = (float*)(ws + SARR(3));
        float* sar = (float*)(ws + SARR(4));
        float* scl = (float*)(ws + SARR(5));
        if (i < V) {
            int r = partial[lane] + partial[64 + lane] + partial[128 + lane] + partial[192 + lane];
            int idx = 8191 - (int)(ki & 0x1FFFull);
            ((int*)(ws + SIDX_OFF))[r] = idx;
            float cx = ((float*)(ws + UARR(0)))[idx];
            float cy = ((float*)(ws + UARR(1)))[idx];
            float w  = ((float*)(ws + UARR(2)))[idx];
            float h  = ((float*)(ws + UARR(3)))[idx];
            float x1 = cx - w / 2.0f;
            float y1 = cy - h / 2.0f;
            float x2 = cx + w / 2.0f;
            float y2 = cy + h / 2.0f;
            sx1[r] = x1; sy1[r] = y1; sx2[r] = x2; sy2[r] = y2;
            sar[r] = fabsf((x2 - x1) * (y2 - y1));  // ref: recomputed from corners
            scl[r] = ((float*)(ws + UARR(5)))[idx];
        } else {                                    // rank positions [V, NPAD): defaults
            ((int*)(ws + SIDX_OFF))[i] = -1;
            sx1[i] = 0.f; sy1[i] = 0.f; sx2[i] = 0.f; sy2[i] = 0.f;
            sar[i] = 0.f; scl[i] = -1.0f;
        }
    }
}

// ---------------- suppression bitmask + compact diag + sparse lists ----------------
__global__ __launch_bounds__(256) void mask_kernel(unsigned char* __restrict__ ws) {
#pragma clang fp contract(off)
    int V = *(int*)(ws + COUNT_OFF);
    if (V > NPAD) V = NPAD;
    int i0 = blockIdx.y * 256;
    int w  = blockIdx.x;
    int j0 = w * 64;
    if (i0 >= V) return;
    if (j0 >= V) return;
    if (j0 + 64 <= i0) return;                     // strictly sub-diagonal: all zero
    int i  = i0 + threadIdx.x;

    const float* sx1 = (const float*)(ws + SARR(0));
    const float* sy1 = (const float*)(ws + SARR(1));
    const float* sx2 = (const float*)(ws + SARR(2));
    const float* sy2 = (const float*)(ws + SARR(3));
    const float* sar = (const float*)(ws + SARR(4));
    const float* scl = (const float*)(ws + SARR(5));

    __shared__ float cx1[64], cy1[64], cx2[64], cy2[64], car[64], ccl[64];
    if (threadIdx.x < 64) {
        int j = j0 + threadIdx.x;
        cx1[threadIdx.x] = sx1[j]; cy1[threadIdx.x] = sy1[j];
        cx2[threadIdx.x] = sx2[j]; cy2[threadIdx.x] = sy2[j];
        car[threadIdx.x] = sar[j]; ccl[threadIdx.x] = scl[j];
    }
    __syncthreads();
    if (i >= V) return;

    unsigned long long word = 0;
    if (j0 + 64 > i + 1) {
        float x1i = sx1[i], y1i = sy1[i], x2i = sx2[i], y2i = sy2[i];
        float ai = sar[i], ci = scl[i];
        for (int jj = 0; jj < 64; ++jj) {
            int j = j0 + jj;
            if (j <= i || j >= V) continue;
            if (ccl[jj] != ci) continue;
            float iw = fminf(x2i, cx2[jj]) - fmaxf(x1i, cx1[jj]);
            iw = fmaxf(iw, 0.0f);
            float ih = fminf(y2i, cy2[jj]) - fmaxf(y1i, cy1[jj]);
            ih = fmaxf(ih, 0.0f);
            float inter = iw * ih;
            float denom = ai + car[jj] - inter + 1e-6f;   // ((ai+aj)-inter)+eps, L-to-R
            if (inter / denom >= 0.5f) word |= (1ull << jj);
        }
    }
    ((unsigned long long*)(ws + MASK_OFF))[(size_t)i * NW + w] = word;
    if (w == (i >> 6))
        ((unsigned long long*)(ws + DIAG_OFF))[i] = word;  // compact diag word

    if (word && V <= VLIM) {                       // sparse list emission
        int pc = __popcll(word);
        unsigned int b = atomicAdd((unsigned int*)(ws + CNT_OFF) + i, (unsigned int)pc);
        unsigned long long t = word;
        unsigned int o = 0;
        while (t) {
            int bit = __builtin_ctzll(t);
            t &= t - 1ull;
            unsigned int slot = b + o; ++o;
            if (slot < LCAP)
                ((unsigned short*)(ws + LIST_OFF))[(size_t)i * LCAP + slot] =
                    (unsigned short)(j0 + bit);
        }
    }
}

// ---------------- greedy scan: ONE wave, coalesced group-of-8 prefetch ----------------
// supp = u64[128] in LDS. Serial path per 64-row chunk:
//   ds_read supp[c] -> scalar greedy resolve (ctz over suppressor rows)
//   -> register-list scatter (LDS atomicOr).
// Prefetch streams (8-16 chunks ahead, unconditional, no dependent branches):
//   diag[row] 512B coalesced, cnt[row] 256B coalesced, lst[row] first 16B.
// Rows with 8<cnt<=16 load the list's 2nd half on demand (rare); cnt>16 falls
// back to mask-row words (V>VLIM always takes that path).

#define LOADG(CN, LA, LB, IW, G) do {                                          \
    int g_ = (G);                                                              \
    _Pragma("unroll") for (int d_ = 0; d_ < 8; ++d_) {                         \
        int cc_  = g_ * 8 + d_;                                                \
        int row_ = (cc_ << 6) + lane;                                          \
        CN[d_] = 0xFFFFFFFFu; LA[d_] = 0; LB[d_] = 0; IW[d_] = 0;              \
        if (cc_ < nch && row_ < V) {                                           \
            IW[d_] = diag[row_];                                               \
            if (useL) {                                                        \
                CN[d_] = cnt[row_];                                            \
                ulonglong2 t2_ = lst[(size_t)row_ * 2];                        \
                LA[d_] = t2_.x; LB[d_] = t2_.y;                                \
            }                                                                  \
        }                                                                      \
    }                                                                          \
} while (0)

__global__ __launch_bounds__(64, 1) void scan_kernel(unsigned char* __restrict__ ws) {
    int lane = threadIdx.x;
    int V = *(const int*)(ws + COUNT_OFF);
    if (V > NPAD) V = NPAD;
    const unsigned long long* mask = (const unsigned long long*)(ws + MASK_OFF);
    const unsigned long long* diag = (const unsigned long long*)(ws + DIAG_OFF);
    const unsigned int*  cnt = (const unsigned int*)(ws + CNT_OFF);
    const ulonglong2*    lst = (const ulonglong2*)(ws + LIST_OFF);
    unsigned long long*  keepw = (unsigned long long*)(ws + KEEP_OFF);

    __shared__ unsigned long long supp[128];       // 8192-bit suppression bitmap
    supp[lane] = 0ull; supp[64 + lane] = 0ull;     // same-wave DS ordering, no barrier

    int nch  = (V + 63) >> 6;
    int maxw = nch;
    bool useL = (V <= VLIM);

    unsigned int cnA[8], cnB[8];
    unsigned long long laA[8], lbA[8], iwA[8], laB[8], lbB[8], iwB[8];

    int ngr = (nch + 7) >> 3;
    if (ngr > 0) LOADG(cnA, laA, lbA, iwA, 0);

    for (int g = 0; g < ngr; ++g) {
        if (g + 1 < ngr) LOADG(cnB, laB, lbB, iwB, g + 1);   // ~24 coalesced loads in flight

        #pragma unroll
        for (int d = 0; d < 8; ++d) {
            int c = g * 8 + d;
            if (c < nch) {
                int base = c << 6;
                int row  = base + lane;

                unsigned long long aw = supp[c];             // LDS broadcast read
                int rem = V - base;
                unsigned long long tail = (rem >= 64) ? ~0ull : ((1ull << rem) - 1ull);
                unsigned long long alive = ~aw & tail;

                unsigned long long inw = iwA[d];             // prefetched diag word
                unsigned long long dnz = __ballot(inw != 0ull);
                unsigned long long work = alive & dnz;
                while (work) {                               // greedy resolve (scalar unit)
                    int k = __builtin_ctzll(work);
                    work &= work - 1ull;
                    unsigned long long dk = readlane64(inw, k);
                    alive &= ~dk;
                    work  &= ~dk;
                }

                bool am = ((alive >> lane) & 1ull) && (row < V);
                unsigned int cA = cnA[d];
                if (am && cA <= LFAST) {                     // common: register list
                    for (unsigned int t = 0; t < cA; ++t) {
                        unsigned int j = ent16(laA[d], lbA[d], (int)t);
                        atomicOr(&supp[j >> 6], 1ull << (j & 63));
                    }
                } else if (am && cA <= LCAP) {               // rare: load 2nd half now
                    ulonglong2 hi = lst[(size_t)row * 2 + 1];
                    for (unsigned int t = 0; t < cA; ++t) {
                        unsigned int j = (t < LFAST) ? ent16(laA[d], lbA[d], (int)t)
                                                     : ent16(hi.x, hi.y, (int)(t - LFAST));
                        atomicOr(&supp[j >> 6], 1ull << (j & 63));
                    }
                }
                unsigned long long ofl = __ballot(am && cA > LCAP);   // overflow / fallback
                while (ofl) {
                    int k = __builtin_ctzll(ofl);
                    ofl &= ofl - 1ull;
                    size_t rb = (size_t)(base + k) * NW;
                    for (int ww = c + lane; ww < maxw; ww += 64) {
                        unsigned long long m = mask[rb + ww];
                        if (m) atomicOr(&supp[ww], m);
                    }
                }
            }
        }

        #pragma unroll
        for (int d = 0; d < 8; ++d) {                        // B -> A
            cnA[d] = cnB[d]; laA[d] = laB[d]; lbA[d] = lbB[d]; iwA[d] = iwB[d];
        }
    }

    keepw[lane]      = ~supp[lane];
    keepw[64 + lane] = ~supp[64 + lane];
}

// ---------------- write output ----------------
__global__ __launch_bounds__(256) void output_kernel(const unsigned char* __restrict__ ws,
                                                     float* __restrict__ out) {
    int r = blockIdx.x * 256 + threadIdx.x;
    if (r >= NBOX) return;
    int V = *(const int*)(ws + COUNT_OFF);
    if (V > NPAD) V = NPAD;
    const unsigned long long* keepw = (const unsigned long long*)(ws + KEEP_OFF);
    bool keep = (r < V) && ((keepw[r >> 6] >> (r & 63)) & 1ull);
    float o0 = 0.f, o1 = 0.f, o2 = 0.f, o3 = 0.f, o4 = 0.f, o5 = 0.f;
    if (keep) {
        int idx = ((const int*)(ws + SIDX_OFF))[r];
        if (idx >= 0 && idx < NBOX) {
            o0 = ((const float*)(ws + UARR(0)))[idx];
            o1 = ((const float*)(ws + UARR(1)))[idx];
            o2 = ((const float*)(ws + UARR(2)))[idx];
            o3 = ((const float*)(ws + UARR(3)))[idx];
            o4 = ((const float*)(ws + UARR(4)))[idx];
            o5 = ((const float*)(ws + UARR(5)))[idx];
        }
    }
    out[r * 6 + 0] = o0;
    out[r * 6 + 1] = o1;
    out[r * 6 + 2] = o2;
    out[r * 6 + 3] = o3;
    out[r * 6 + 4] = o4;
    out[r * 6 + 5] = o5;
}

extern "C" void kernel_launch(void* const* d_in, const int* in_sizes, int n_in,
                              void* d_out, int out_size, void* d_ws, size_t ws_size,
                              hipStream_t stream) {
    const float* x       = (const float*)d_in[0];
    const float* anchors = (const float*)d_in[1];
    float* out           = (float*)d_out;
    unsigned char* ws    = (unsigned char*)d_ws;

    hipMemsetAsync(ws + COUNT_OFF, 0, 4, stream);          // zero valid-count only
    decode_kernel<<<125, 64, 0, stream>>>(x, anchors, ws);
    rank_scatter_kernel<<<NPAD / 64, 256, 0, stream>>>(ws);
    dim3 mgrid(NW, NPAD / 256);
    mask_kernel<<<mgrid, 256, 0, stream>>>(ws);
    scan_kernel<<<1, 64, 0, stream>>>(ws);
    output_kernel<<<(NBOX + 255) / 256, 256, 0, stream>>>(ws, out);
}

// Round 10
// 131.583 us; speedup vs baseline: 1.1776x; 1.1505x over previous
//
#include <hip/hip_runtime.h>
#include <stdint.h>

#define NBOX 8000
#define NPAD 8192

// ---- workspace layout (bytes) ----
#define COUNT_OFF 0                          // u32 valid count (memset 0)
#define ECNT_OFF  4                          // u32 edge count  (memset 0)
#define VKEYS_OFF 0x9000                     // 8192 * 8
#define U_OFF     0x20000                    // 6 unsorted arrays
#define UARR(i)   (U_OFF + (size_t)(i) * NPAD * 4)   // bx,by,bw,bh,conf,cls
#define SIDX_OFF  0x50000                    // int[8192]
#define SARR(i)   (0x58000 + (size_t)(i) * NPAD * 4) // x1,y1,x2,y2,area,cls
#define EDGE_OFF  (size_t)0x200000           // u32 edges (i<<13|j); max V^2/2 = 134MB < ws

__device__ __forceinline__ float sigmoidf_(float x) {
    return 1.0f / (1.0f + expf(-x));
}

// ---------------- decode: 1 wave/block, wave-aggregated key compaction ----------------
__global__ __launch_bounds__(64) void decode_kernel(const float* __restrict__ x,
                                                    const float* __restrict__ anchors,
                                                    unsigned char* __restrict__ ws) {
    int n = blockIdx.x * 64 + threadIdx.x;          // 125*64 = 8000 exactly
    int a   = n / 1600;
    int pos = n - a * 1600;
    int gy  = pos / 40;
    int gx  = pos - gy * 40;
    const float* p = x + (size_t)a * 25 * 1600 + pos;

    float tx   = sigmoidf_(p[0]);
    float ty   = sigmoidf_(p[1600]);
    float tw   = p[2 * 1600];
    float th   = p[3 * 1600];
    float conf = sigmoidf_(p[4 * 1600]);

    float best = -1.0f; int bi = 0;
    #pragma unroll
    for (int c = 0; c < 20; ++c) {                  // first-max wins, matches jnp.argmax
        float v = sigmoidf_(p[(5 + c) * 1600]);
        if (v > best) { best = v; bi = c; }
    }

    float aw = anchors[a * 2 + 0];
    float ah = anchors[a * 2 + 1];
    float bx = (tx + (float)gx) * 8.0f;
    float by = (ty + (float)gy) * 8.0f;
    float bw = expf(tw) * aw * 8.0f;
    float bh = expf(th) * ah * 8.0f;

    ((float*)(ws + UARR(0)))[n] = bx;
    ((float*)(ws + UARR(1)))[n] = by;
    ((float*)(ws + UARR(2)))[n] = bw;
    ((float*)(ws + UARR(3)))[n] = bh;
    ((float*)(ws + UARR(4)))[n] = conf;
    ((float*)(ws + UARR(5)))[n] = (float)bi;

    bool valid = conf > 0.5f;                       // strict >, matches ref
    unsigned long long bal = __ballot(valid);
    if (bal) {
        int lead = __builtin_ctzll(bal);
        unsigned int base = 0;
        if ((int)threadIdx.x == lead)
            base = atomicAdd((unsigned int*)(ws + COUNT_OFF), (unsigned int)__popcll(bal));
        base = (unsigned int)__shfl((int)base, lead, 64);
        if (valid) {
            unsigned int cb = __float_as_uint(conf);   // conf in (0,1): bits monotonic
            unsigned long long key = ((unsigned long long)cb << 32) | (unsigned long long)(8191 - n);
            unsigned int slot = base + (unsigned int)__popcll(bal & ((1ull << threadIdx.x) - 1ull));
            ((unsigned long long*)(ws + VKEYS_OFF))[slot] = key;
        }
    }
}

// ---------------- block-complete rank + scatter (one pass, no atomics) ----------------
__global__ __launch_bounds__(256) void rank_scatter_kernel(unsigned char* __restrict__ ws) {
#pragma clang fp contract(off)
    __shared__ unsigned long long tile[256];
    __shared__ int partial[256];
    int V = *(const int*)(ws + COUNT_OFF);
    if (V > NPAD) V = NPAD;
    int tid  = threadIdx.x;
    int lane = tid & 63;
    int q    = tid >> 6;                            // quarter 0..3
    int b    = blockIdx.x;                          // 128 blocks
    int i    = (b << 6) + lane;                     // row owned by this lane

    const unsigned long long* vk = (const unsigned long long*)(ws + VKEYS_OFF);
    unsigned long long ki = (i < V) ? vk[i] : ~0ull;
    int cnt = 0;
    if ((b << 6) < V) {                             // block-uniform
        int ntiles = (V + 255) >> 8;
        for (int tb = 0; tb < ntiles; ++tb) {
            int j = (tb << 8) + tid;
            tile[tid] = (j < V) ? vk[j] : 0ull;     // pad 0 never counts (keys > 0)
            __syncthreads();
            int basej = (tb << 8) + (q << 6);
            int lim = V - basej;
            if (lim > 64) lim = 64;
            const unsigned long long* tq = &tile[q << 6];
            if (lim == 64) {
                #pragma unroll 16
                for (int jj = 0; jj < 64; ++jj) cnt += (tq[jj] > ki) ? 1 : 0;
            } else {
                for (int jj = 0; jj < lim; ++jj) cnt += (tq[jj] > ki) ? 1 : 0;
            }
            __syncthreads();
        }
    }
    partial[tid] = cnt;
    __syncthreads();
    if (q == 0) {
        float* sx1 = (float*)(ws + SARR(0));
        float* sy1 = (float*)(ws + SARR(1));
        float* sx2 = (float*)(ws + SARR(2));
        float* sy2 = (float*)(ws + SARR(3));
        float* sar = (float*)(ws + SARR(4));
        float* scl = (float*)(ws + SARR(5));
        if (i < V) {
            int r = partial[lane] + partial[64 + lane] + partial[128 + lane] + partial[192 + lane];
            int idx = 8191 - (int)(ki & 0x1FFFull);
            ((int*)(ws + SIDX_OFF))[r] = idx;
            float cx = ((float*)(ws + UARR(0)))[idx];
            float cy = ((float*)(ws + UARR(1)))[idx];
            float w  = ((float*)(ws + UARR(2)))[idx];
            float h  = ((float*)(ws + UARR(3)))[idx];
            float x1 = cx - w / 2.0f;
            float y1 = cy - h / 2.0f;
            float x2 = cx + w / 2.0f;
            float y2 = cy + h / 2.0f;
            sx1[r] = x1; sy1[r] = y1; sx2[r] = x2; sy2[r] = y2;
            sar[r] = fabsf((x2 - x1) * (y2 - y1));  // ref: recomputed from corners
            scl[r] = ((float*)(ws + UARR(5)))[idx];
        } else {                                    // rank positions [V, NPAD): defaults
            ((int*)(ws + SIDX_OFF))[i] = -1;
            sx1[i] = 0.f; sy1[i] = 0.f; sx2[i] = 0.f; sy2[i] = 0.f;
            sar[i] = 0.f; scl[i] = -1.0f;
        }
    }
}

// ---------------- suppression edges: (i<<13|j) for j>i, same cls, IoU>=0.5 ----------------
// Wave-aggregated compaction: shfl inclusive-scan of per-lane popcounts, one
// global atomicAdd per nonzero wave. No bitmask matrix, no lists, no caps.
__global__ __launch_bounds__(256) void mask_kernel(unsigned char* __restrict__ ws) {
#pragma clang fp contract(off)
    int V = *(int*)(ws + COUNT_OFF);
    if (V > NPAD) V = NPAD;
    int i0 = blockIdx.y * 256;
    int w  = blockIdx.x;
    int j0 = w * 64;
    if (i0 >= V) return;                           // block-uniform exits only
    if (j0 >= V) return;
    if (j0 + 64 <= i0) return;                     // strictly sub-diagonal: empty
    int tid  = threadIdx.x;
    int lane = tid & 63;
    int i    = i0 + tid;

    const float* sx1 = (const float*)(ws + SARR(0));
    const float* sy1 = (const float*)(ws + SARR(1));
    const float* sx2 = (const float*)(ws + SARR(2));
    const float* sy2 = (const float*)(ws + SARR(3));
    const float* sar = (const float*)(ws + SARR(4));
    const float* scl = (const float*)(ws + SARR(5));

    __shared__ float cx1[64], cy1[64], cx2[64], cy2[64], car[64], ccl[64];
    if (tid < 64) {
        int j = j0 + tid;                          // SARR defined for all 8192
        cx1[tid] = sx1[j]; cy1[tid] = sy1[j];
        cx2[tid] = sx2[j]; cy2[tid] = sy2[j];
        car[tid] = sar[j]; ccl[tid] = scl[j];
    }
    __syncthreads();

    unsigned long long word = 0;
    if (i < V && j0 + 64 > i + 1) {
        float x1i = sx1[i], y1i = sy1[i], x2i = sx2[i], y2i = sy2[i];
        float ai = sar[i], ci = scl[i];
        for (int jj = 0; jj < 64; ++jj) {
            int j = j0 + jj;
            if (j <= i || j >= V) continue;
            if (ccl[jj] != ci) continue;
            float iw = fminf(x2i, cx2[jj]) - fmaxf(x1i, cx1[jj]);
            iw = fmaxf(iw, 0.0f);
            float ih = fminf(y2i, cy2[jj]) - fmaxf(y1i, cy1[jj]);
            ih = fmaxf(ih, 0.0f);
            float inter = iw * ih;
            float denom = ai + car[jj] - inter + 1e-6f;   // ((ai+aj)-inter)+eps, L-to-R
            if (inter / denom >= 0.5f) word |= (1ull << jj);
        }
    }

    // wave-aggregated edge emission (all 64 lanes participate)
    int pc = __popcll(word);
    int scan = pc;
    #pragma unroll
    for (int d = 1; d < 64; d <<= 1) {
        int t = __shfl_up(scan, d, 64);
        if (lane >= d) scan += t;
    }
    int total = __shfl(scan, 63, 64);
    unsigned int base = 0;
    if (total > 0) {
        if (lane == 63)
            base = atomicAdd((unsigned int*)(ws + ECNT_OFF), (unsigned int)total);
        base = (unsigned int)__shfl((int)base, 63, 64);
        unsigned int off = base + (unsigned int)(scan - pc);   // exclusive prefix
        unsigned int* edges = (unsigned int*)(ws + EDGE_OFF);
        unsigned long long t = word;
        while (t) {
            int bit = __builtin_ctzll(t);
            t &= t - 1ull;
            edges[off++] = ((unsigned int)i << 13) | (unsigned int)(j0 + bit);
        }
    }
}

// ---------------- NMS via Jacobi fixed point + fused output ----------------
// Greedy NMS == unique fixed point of a[j] = valid[j] & ~OR_{i<j, edge} a[i].
// Jacobi from all-alive converges in maxdepth (longest suppression chain)
// iterations; every iteration is edge-parallel. Single block, LDS bitmaps,
// exact change-detection (no iteration cap needed: fixed point is unique).
__global__ __launch_bounds__(1024, 1) void nms_out_kernel(unsigned char* __restrict__ ws,
                                                          float* __restrict__ out) {
    int tid = threadIdx.x;
    int V = *(const int*)(ws + COUNT_OFF);
    if (V > NPAD) V = NPAD;
    unsigned int E = *(const unsigned int*)(ws + ECNT_OFF);
    const unsigned int* edges = (const unsigned int*)(ws + EDGE_OFF);

    __shared__ unsigned long long alive[128], supp[128];
    __shared__ int flag;

    if (tid < 128) {                               // init: all valid rows alive
        int base = tid << 6;
        int rem = V - base;
        alive[tid] = (rem >= 64) ? ~0ull : (rem > 0 ? ((1ull << rem) - 1ull) : 0ull);
    }
    __syncthreads();

    for (;;) {
        if (tid < 128) supp[tid] = 0ull;
        __syncthreads();
        for (unsigned int e = tid; e < E; e += 1024) {
            unsigned int u = edges[e];
            unsigned int i = u >> 13, j = u & 8191u;
            if ((alive[i >> 6] >> (i & 63)) & 1ull)
                atomicOr(&supp[j >> 6], 1ull << (j & 63));
        }
        if (tid == 0) flag = 0;
        __syncthreads();
        if (tid < 128) {
            int base = tid << 6;
            int rem = V - base;
            unsigned long long init = (rem >= 64) ? ~0ull : (rem > 0 ? ((1ull << rem) - 1ull) : 0ull);
            unsigned long long na = init & ~supp[tid];
            if (na != alive[tid]) { alive[tid] = na; flag = 1; }
        }
        __syncthreads();
        if (!flag) break;
    }

    // fused output: kept ranks get box values, everything else zero
    for (int r = tid; r < NBOX; r += 1024) {
        bool keep = (r < V) && ((alive[r >> 6] >> (r & 63)) & 1ull);
        float o0 = 0.f, o1 = 0.f, o2 = 0.f, o3 = 0.f, o4 = 0.f, o5 = 0.f;
        if (keep) {
            int idx = ((const int*)(ws + SIDX_OFF))[r];
            if (idx >= 0 && idx < NBOX) {
                o0 = ((const float*)(ws + UARR(0)))[idx];
                o1 = ((const float*)(ws + UARR(1)))[idx];
                o2 = ((const float*)(ws + UARR(2)))[idx];
                o3 = ((const float*)(ws + UARR(3)))[idx];
                o4 = ((const float*)(ws + UARR(4)))[idx];
                o5 = ((const float*)(ws + UARR(5)))[idx];
            }
        }
        out[r * 6 + 0] = o0;
        out[r * 6 + 1] = o1;
        out[r * 6 + 2] = o2;
        out[r * 6 + 3] = o3;
        out[r * 6 + 4] = o4;
        out[r * 6 + 5] = o5;
    }
}

extern "C" void kernel_launch(void* const* d_in, const int* in_sizes, int n_in,
                              void* d_out, int out_size, void* d_ws, size_t ws_size,
                              hipStream_t stream) {
    const float* x       = (const float*)d_in[0];
    const float* anchors = (const float*)d_in[1];
    float* out           = (float*)d_out;
    unsigned char* ws    = (unsigned char*)d_ws;

    hipMemsetAsync(ws, 0, 8, stream);              // zero valid-count + edge-count
    decode_kernel<<<125, 64, 0, stream>>>(x, anchors, ws);
    rank_scatter_kernel<<<NPAD / 64, 256, 0, stream>>>(ws);
    dim3 mgrid(128, NPAD / 256);
    mask_kernel<<<mgrid, 256, 0, stream>>>(ws);
    nms_out_kernel<<<1, 1024, 0, stream>>>(ws, out);
}